// Round 3
// baseline (361.232 us; speedup 1.0000x reference)
//
#include <hip/hip_runtime.h>
#include <cstdint>

#define TB 2048     // T
#define DIM 2560    // D
#define NQ 8
#define NKV 4
#define HDIM 256
#define WIN 1024
#define KMASK -2.3819763e+38f

using f32x4 = __attribute__((ext_vector_type(4))) float;
using s16x8 = __attribute__((ext_vector_type(8))) short;
using u16x4 = __attribute__((ext_vector_type(4))) unsigned short;

__device__ __forceinline__ unsigned short f2bf(float f) {
  uint32_t x = __builtin_bit_cast(uint32_t, f);
  x += 0x7FFFu + ((x >> 16) & 1u);
  return (unsigned short)(x >> 16);
}

// ---------- pack W1: 16 heads of (DIM x HDIM) f32 -> W1[c][d] bf16 (c = head*256+h) ----------
__global__ __launch_bounds__(256) void k_packw1(const float* __restrict__ q_w,
                                                const float* __restrict__ kv_w,
                                                unsigned short* __restrict__ W1) {
  __shared__ float tile[32][33];
  const int hd = blockIdx.z;  // 0..7 q heads, 8..11 k heads, 12..15 v heads
  const float* src = (hd < 8) ? (q_w + (size_t)hd * DIM * HDIM)
                              : (kv_w + (size_t)(hd - 8) * DIM * HDIM);
  unsigned short* dst = W1 + (size_t)hd * HDIM * DIM;
  const int c0 = blockIdx.x * 32, r0 = blockIdx.y * 32;  // c over HDIM, r over DIM
  const int tx = threadIdx.x & 31, ty = threadIdx.x >> 5;
#pragma unroll
  for (int i = 0; i < 32; i += 8)
    tile[ty + i][tx] = src[(size_t)(r0 + ty + i) * HDIM + c0 + tx];
  __syncthreads();
#pragma unroll
  for (int i = 0; i < 32; i += 8)
    dst[(size_t)(c0 + ty + i) * DIM + r0 + tx] = f2bf(tile[tx][ty + i]);
}

// ---------- generic transpose f32 (RxC) -> bf16 (CxR) ----------
__global__ __launch_bounds__(256) void k_tconv(const float* __restrict__ src,
                                               unsigned short* __restrict__ dst,
                                               int R, int C) {
  __shared__ float tile[32][33];
  const int c0 = blockIdx.x * 32, r0 = blockIdx.y * 32;
  const int tx = threadIdx.x & 31, ty = threadIdx.x >> 5;
#pragma unroll
  for (int i = 0; i < 32; i += 8)
    tile[ty + i][tx] = src[(size_t)(r0 + ty + i) * C + c0 + tx];
  __syncthreads();
#pragma unroll
  for (int i = 0; i < 32; i += 8)
    dst[(size_t)(c0 + ty + i) * R + r0 + tx] = f2bf(tile[tx][ty + i]);
}

// ---------- f32 -> bf16 elementwise (4/thread) ----------
__global__ __launch_bounds__(256) void k_cvt(const float* __restrict__ src,
                                             unsigned short* __restrict__ dst, int n4) {
  int i = blockIdx.x * 256 + threadIdx.x;
  if (i < n4) {
    f32x4 v = *(const f32x4*)&src[(size_t)i * 4];
    u16x4 o;
#pragma unroll
    for (int j = 0; j < 4; ++j) o[j] = f2bf(v[j]);
    *(u16x4*)&dst[(size_t)i * 4] = o;
  }
}

// ---------- 256x128 tile bf16 GEMM, 3-buffer counted-vmcnt pipeline ----------
// C[M][Nc] = A[M][Kd] * Bw[Nc][Kd]^T.  512 threads = 8 waves (4M x 2N), per-wave 64x64.
// LDS: 3 ring buffers, XOR-swizzled (source-side inverse swizzle, read-side swizzle).
__global__ __launch_bounds__(512, 2) void k_gemm(const unsigned short* __restrict__ A,
                                                 const unsigned short* __restrict__ Bw,
                                                 float* __restrict__ Cc,
                                                 int M, int Nc, int Kd, int nbn) {
  __shared__ unsigned short shA[3][256 * 64];
  __shared__ unsigned short shB[3][128 * 64];
  const int tid = threadIdx.x, w = tid >> 6, l = tid & 63;
  // bijective XCD swizzle (nwg % 8 == 0)
  const int nwg = gridDim.x;
  const int bid = blockIdx.x;
  const int swzb = (bid & 7) * (nwg >> 3) + (bid >> 3);
  const int m0 = (swzb / nbn) * 256, n0 = (swzb % nbn) * 128;

  const int srow = l >> 3;                           // staging row within 8-row group
  const int sw_colb = (((l & 7) ^ srow) << 4);       // inverse-swizzled source column (bytes)
  const int wrow = w * 8;
  const int NT = Kd >> 6;

#define GSTAGE(buf, t)                                                                      \
  {                                                                                         \
    const int kt = (t) << 6;                                                                \
    _Pragma("unroll") for (int r = 0; r < 4; ++r) {                                         \
      const char* src = (const char*)A + ((size_t)(m0 + r * 64 + wrow + srow) * Kd + kt) * 2 + sw_colb; \
      __builtin_amdgcn_global_load_lds(                                                     \
          (__attribute__((address_space(1))) void*)src,                                     \
          (__attribute__((address_space(3))) void*)((char*)&shA[buf][0] + r * 8192 + w * 1024), \
          16, 0, 0);                                                                        \
    }                                                                                       \
    _Pragma("unroll") for (int r = 0; r < 2; ++r) {                                         \
      const char* src = (const char*)Bw + ((size_t)(n0 + r * 64 + wrow + srow) * Kd + kt) * 2 + sw_colb; \
      __builtin_amdgcn_global_load_lds(                                                     \
          (__attribute__((address_space(1))) void*)src,                                     \
          (__attribute__((address_space(3))) void*)((char*)&shB[buf][0] + r * 8192 + w * 1024), \
          16, 0, 0);                                                                        \
    }                                                                                       \
  }

  const int wm = w >> 1, wn = w & 1;
  const int lr = l & 15, lg = l >> 4;
  f32x4 acc[4][4] = {};

  GSTAGE(0, 0);
  GSTAGE(1, 1);
  asm volatile("s_waitcnt vmcnt(6)" ::: "memory");
  __builtin_amdgcn_s_barrier();

  for (int t = 0; t < NT; ++t) {
    const int buf = t % 3;
    const bool pf = (t + 2 < NT);
    if (pf) GSTAGE((t + 2) % 3, t + 2);

    const char* sa = (const char*)&shA[buf][0];
    const char* sb = (const char*)&shB[buf][0];
#pragma unroll
    for (int kk = 0; kk < 2; ++kk) {
      s16x8 af[4], bfr[4];
      const int cb = kk * 64 + lg * 16;
#pragma unroll
      for (int mi = 0; mi < 4; ++mi) {
        int row = wm * 64 + mi * 16 + lr;
        af[mi] = *(const s16x8*)(sa + row * 128 + (cb ^ ((row & 7) << 4)));
      }
#pragma unroll
      for (int ni = 0; ni < 4; ++ni) {
        int row = wn * 64 + ni * 16 + lr;
        bfr[ni] = *(const s16x8*)(sb + row * 128 + (cb ^ ((row & 7) << 4)));
      }
      __builtin_amdgcn_s_setprio(1);
#pragma unroll
      for (int mi = 0; mi < 4; ++mi)
#pragma unroll
        for (int ni = 0; ni < 4; ++ni)
          acc[mi][ni] = __builtin_amdgcn_mfma_f32_16x16x32_bf16(af[mi], bfr[ni], acc[mi][ni], 0, 0, 0);
      __builtin_amdgcn_s_setprio(0);
    }
    if (pf) {
      asm volatile("s_waitcnt vmcnt(6)" ::: "memory");
    } else {
      asm volatile("s_waitcnt vmcnt(0)" ::: "memory");
    }
    __builtin_amdgcn_s_barrier();
  }
#undef GSTAGE

#pragma unroll
  for (int mi = 0; mi < 4; ++mi)
#pragma unroll
    for (int ni = 0; ni < 4; ++ni) {
      size_t base = (size_t)(m0 + wm * 64 + mi * 16 + lg * 4) * Nc + (n0 + wn * 64 + ni * 16 + lr);
#pragma unroll
      for (int i = 0; i < 4; ++i)
        Cc[base + (size_t)i * Nc] = acc[mi][ni][i];
    }
}

// ---------- RMSNorm + RoPE for q/k channels of Y; writes bf16 Q[B][NQ][T][H], K[B][NKV][T][H] ----------
__global__ __launch_bounds__(256) void k_normrope(const float* __restrict__ Y,
                                                  const float* __restrict__ qsc,
                                                  const float* __restrict__ ksc,
                                                  const int* __restrict__ pos,
                                                  unsigned short* __restrict__ Q,
                                                  unsigned short* __restrict__ Kb) {
  __shared__ float s_sin[128], s_cos[128];
  const int bt = blockIdx.x;
  const int b = bt >> 11, t = bt & (TB - 1);
  const int tid = threadIdx.x;
  float p = (float)pos[bt];
  if (tid < 128) {
    float fr = (float)tid * (1.0f / 128.0f);
    float inv_ts = __expf(fr * -9.210340371976184f);  // 10000^-fr
    float ang = p * inv_ts;
    float sv, cv;
    sincosf(ang, &sv, &cv);
    s_sin[tid] = sv;
    s_cos[tid] = cv;
  }
  __syncthreads();
  const int w = tid >> 6, l = tid & 63;
  const int jj0 = (l & 31) * 4;
  for (int sidx = w; sidx < 12; sidx += 4) {  // 0..7 q heads, 8..11 k heads
    const float* src = Y + (size_t)bt * 4096 + sidx * 256;
    f32x4 v = *(const f32x4*)&src[l * 4];
    float ss = v[0] * v[0] + v[1] * v[1] + v[2] * v[2] + v[3] * v[3];
#pragma unroll
    for (int d = 1; d < 64; d <<= 1) ss += __shfl_xor(ss, d);
    float rs = rsqrtf(ss * (1.0f / 256.0f) + 1e-6f);
    const float* scp = (sidx < 8) ? qsc : ksc;
    float nv[4], res[4];
#pragma unroll
    for (int j = 0; j < 4; ++j) nv[j] = v[j] * rs * (1.0f + scp[l * 4 + j]);
#pragma unroll
    for (int j = 0; j < 4; ++j) {
      float o = __shfl_xor(nv[j], 32);
      float sn = s_sin[jj0 + j], cs = s_cos[jj0 + j];
      res[j] = (l < 32) ? (nv[j] * cs - o * sn) : (nv[j] * cs + o * sn);
    }
    float qs = (sidx < 8) ? 0.0625f : 1.0f;  // H^-0.5 = 1/16 folded into q
    u16x4 ob;
#pragma unroll
    for (int j = 0; j < 4; ++j) ob[j] = f2bf(res[j] * qs);
    if (sidx < 8) {
      size_t di = ((size_t)(b * NQ + sidx) * TB + t) * HDIM + l * 4;
      *(u16x4*)&Q[di] = ob;
    } else {
      size_t di = ((size_t)(b * NKV + (sidx - 8)) * TB + t) * HDIM + l * 4;
      *(u16x4*)&Kb[di] = ob;
    }
  }
}

// ---------- transpose v channels of Y -> VT[B][NKV][H][T] bf16 ----------
__global__ __launch_bounds__(256) void k_vtrans(const float* __restrict__ Y,
                                                unsigned short* __restrict__ VT) {
  __shared__ float tile[64][65];
  const int t0 = blockIdx.x * 64, h0 = blockIdx.y * 64;
  const int z = blockIdx.z;  // b*4+kh
  const int bq = z >> 2, kh = z & 3;
  const int tid = threadIdx.x;
#pragma unroll
  for (int rep = 0; rep < 16; ++rep) {
    int idx = rep * 256 + tid;
    int tr = idx >> 6, hc = idx & 63;
    tile[tr][hc] = Y[(size_t)(bq * TB + t0 + tr) * 4096 + 3072 + kh * 256 + h0 + hc];
  }
  __syncthreads();
#pragma unroll
  for (int rep = 0; rep < 16; ++rep) {
    int idx = rep * 256 + tid;
    int hr = idx >> 6, tc = idx & 63;
    VT[((size_t)z * 256 + h0 + hr) * TB + t0 + tc] = f2bf(tile[tc][hr]);
  }
}

// ---------- flash attention: LDS-staged K/V tiles, double-buffered, 4 waves share ----------
__global__ __launch_bounds__(256, 2) void k_attn(const unsigned short* __restrict__ Q,
                                                 const unsigned short* __restrict__ Kb,
                                                 const unsigned short* __restrict__ VT,
                                                 unsigned short* __restrict__ ENC) {
  __shared__ unsigned short shK[2][32 * 256];  // [s-row][h], 512B rows, XOR-swizzled
  __shared__ unsigned short shV[2][256 * 32];  // [h-row][s], 64B rows, natural layout
  __shared__ unsigned short Pb[4][512];
  const int tid = threadIdx.x, w = tid >> 6, l = tid & 63;
  const int bn = blockIdx.y;
  const int b = bn >> 3, n = bn & 7, kh = n >> 1;
  const int t0b = blockIdx.x * 64;
  const int t0 = t0b + w * 16;
  const int lr = l & 15, lg = l >> 4;
  const unsigned short* qp = Q + ((size_t)bn * TB + t0) * HDIM;
  const char* kbase = (const char*)(Kb + ((size_t)(b * NKV + kh) * TB) * HDIM);
  const char* vbase = (const char*)(VT + ((size_t)(b * NKV + kh) * HDIM) * TB);

  s16x8 aq[8];
#pragma unroll
  for (int kk = 0; kk < 8; ++kk)
    aq[kk] = *(const s16x8*)&qp[lr * HDIM + kk * 32 + lg * 8];

  f32x4 o[16] = {};
  float mrow[4], lsum[4];
#pragma unroll
  for (int i = 0; i < 4; ++i) { mrow[i] = -__builtin_inff(); lsum[i] = 0.f; }

  int lo = t0b - (WIN - 1);
  if (lo < 0) lo = 0;
  lo &= ~31;
  const int nsteps = (t0b + 32 - lo) / 32 + 1;

  // stage K-tile (32x256, source-swizzled) + V-tile (256x32) for key block s0
  const int k_row = (w << 1) + (l >> 5);           // within 8-row group per issue
  const int k_colb = (l & 31) * 16;                // byte col 0..496
  const int v_row = (w << 4) + (l >> 2);           // within 64-row group per issue
  const int v_colb = (l & 3) * 16;                 // byte col 0..48
#define STAGE(buf, s0)                                                                       \
  {                                                                                          \
    _Pragma("unroll") for (int r = 0; r < 4; ++r) {                                          \
      int row = r * 8 + k_row;                                                               \
      int scol = k_colb ^ ((row & 7) << 4);                                                  \
      const char* src = kbase + (size_t)((s0) + row) * 512 + scol;                           \
      __builtin_amdgcn_global_load_lds(                                                      \
          (__attribute__((address_space(1))) void*)src,                                      \
          (__attribute__((address_space(3))) void*)((char*)&shK[buf][0] + r * 4096 + w * 1024), \
          16, 0, 0);                                                                         \
    }                                                                                        \
    _Pragma("unroll") for (int r = 0; r < 4; ++r) {                                          \
      int row = r * 64 + v_row;                                                              \
      const char* src = vbase + (size_t)row * (TB * 2) + (size_t)(s0) * 2 + v_colb;          \
      __builtin_amdgcn_global_load_lds(                                                      \
          (__attribute__((address_space(1))) void*)src,                                      \
          (__attribute__((address_space(3))) void*)((char*)&shV[buf][0] + r * 4096 + w * 1024), \
          16, 0, 0);                                                                         \
    }                                                                                        \
  }

  STAGE(0, lo);
  __syncthreads();

  for (int step = 0; step < nsteps; ++step) {
    const int s0 = lo + step * 32;
    const int buf = step & 1;
    if (step + 1 < nsteps) STAGE(buf ^ 1, s0 + 32);

    const bool active = (s0 <= t0 + 15) && (s0 + 31 >= t0 - (WIN - 1));
    if (active) {
      // QK^T from LDS (swizzled read)
      f32x4 sacc[2] = {};
      const char* kt = (const char*)&shK[buf][0];
      const int swz = (lr & 7) << 4;
#pragma unroll
      for (int cb = 0; cb < 2; ++cb) {
        const int rb = (cb * 16 + lr) * 512;
#pragma unroll
        for (int kk = 0; kk < 8; ++kk) {
          s16x8 bk = *(const s16x8*)(kt + rb + ((kk * 64 + lg * 16) ^ swz));
          sacc[cb] = __builtin_amdgcn_mfma_f32_16x16x32_bf16(aq[kk], bk, sacc[cb], 0, 0, 0);
        }
      }
      float r_[4], p0[4], p1[4];
#pragma unroll
      for (int i = 0; i < 4; ++i) {
        int trow = t0 + lg * 4 + i;
        int sA = s0 + lr, sB = s0 + 16 + lr;
        float svA = ((sA <= trow) && (trow - sA < WIN)) ? sacc[0][i] : KMASK;
        float svB = ((sB <= trow) && (trow - sB < WIN)) ? sacc[1][i] : KMASK;
        float mx = fmaxf(svA, svB);
#pragma unroll
        for (int d = 1; d < 16; d <<= 1) mx = fmaxf(mx, __shfl_xor(mx, d));
        float mnew = fmaxf(mrow[i], mx);
        float r = __expf(mrow[i] - mnew);
        float pa = __expf(svA - mnew);
        float pb = __expf(svB - mnew);
        float bs = pa + pb;
#pragma unroll
        for (int d = 1; d < 16; d <<= 1) bs += __shfl_xor(bs, d);
        lsum[i] = lsum[i] * r + bs;
        mrow[i] = mnew;
        r_[i] = r; p0[i] = pa; p1[i] = pb;
      }
#pragma unroll
      for (int hb = 0; hb < 16; ++hb)
#pragma unroll
        for (int i = 0; i < 4; ++i) o[hb][i] *= r_[i];
      // C-layout -> A-layout via per-wave LDS buffer
#pragma unroll
      for (int i = 0; i < 4; ++i) {
        int row = lg * 4 + i;
        Pb[w][row * 32 + lr] = f2bf(p0[i]);
        Pb[w][row * 32 + 16 + lr] = f2bf(p1[i]);
      }
      asm volatile("s_waitcnt lgkmcnt(0)" ::: "memory");
      s16x8 pfrag = *(const s16x8*)&Pb[w][lr * 32 + lg * 8];
      // PV from LDS V-tile
      const char* vt = (const char*)&shV[buf][0];
#pragma unroll
      for (int hb = 0; hb < 16; ++hb) {
        s16x8 vb = *(const s16x8*)(vt + (hb * 16 + lr) * 64 + lg * 16);
        o[hb] = __builtin_amdgcn_mfma_f32_16x16x32_bf16(pfrag, vb, o[hb], 0, 0, 0);
      }
    }
    __syncthreads();
  }
#undef STAGE

#pragma unroll
  for (int i = 0; i < 4; ++i) {
    int trow = t0 + lg * 4 + i;
    float inv = 1.0f / lsum[i];
    size_t rb = (size_t)(b * TB + trow) * 2048 + n * HDIM;
#pragma unroll
    for (int hb = 0; hb < 16; ++hb)
      ENC[rb + hb * 16 + lr] = f2bf(o[hb][i] * inv);
  }
}

extern "C" void kernel_launch(void* const* d_in, const int* in_sizes, int n_in,
                              void* d_out, int out_size, void* d_ws, size_t ws_size,
                              hipStream_t stream) {
  (void)in_sizes; (void)n_in; (void)out_size; (void)ws_size;
  const float* x = (const float*)d_in[0];
  const float* q_w = (const float*)d_in[1];
  const float* kv_w = (const float*)d_in[2];
  const float* qsc = (const float*)d_in[3];
  const float* ksc = (const float*)d_in[4];
  const float* out_w = (const float*)d_in[5];
  const int* pos = (const int*)d_in[6];
  float* out = (float*)d_out;

  char* ws = (char*)d_ws;
  unsigned short* W1 = (unsigned short*)(ws);              // 4096x2560 bf16 (20.97 MB)
  unsigned short* W3 = (unsigned short*)(ws + 20971520);   // 2560x2048 bf16 (10.49 MB)
  unsigned short* XB = (unsigned short*)(ws + 31457280);   // 4096x2560 bf16 (20.97 MB)
  float* Y = (float*)(ws + 52428800);                      // 4096x4096 f32  (67.1 MB)
  unsigned short* KB = (unsigned short*)(ws + 119537664);  // 2x4x2048x256 bf16 (8.39 MB)
  unsigned short* VT = (unsigned short*)(ws + 127926272);  // 2x4x256x2048 bf16 (8.39 MB)
  unsigned short* Qb = XB;                                 // reuse XB after GEMM1
  unsigned short* ENC = (unsigned short*)(ws + 52428800);  // reuse Y after norm/vtrans

  k_packw1<<<dim3(8, 80, 16), 256, 0, stream>>>(q_w, kv_w, W1);
  k_tconv<<<dim3(80, 64), 256, 0, stream>>>(out_w, W3, 2048, DIM);
  k_cvt<<<dim3(10240), 256, 0, stream>>>(x, XB, 2621440);
  // GEMM1: M=4096, N=4096, K=2560 -> 16 x 32 = 512 blocks
  k_gemm<<<dim3(512), 512, 0, stream>>>(XB, W1, Y, 4096, 4096, DIM, 32);
  k_normrope<<<dim3(4096), 256, 0, stream>>>(Y, qsc, ksc, pos, Qb, KB);
  k_vtrans<<<dim3(32, 4, 8), 256, 0, stream>>>(Y, VT);
  k_attn<<<dim3(32, 16), 256, 0, stream>>>(Qb, KB, VT, ENC);
  // GEMM3: M=4096, N=2560, K=2048 -> 16 x 20 = 320 blocks
  k_gemm<<<dim3(320), 512, 0, stream>>>(ENC, W3, out, 4096, DIM, 2048, 20);
}

// Round 4
// 297.421 us; speedup vs baseline: 1.2145x; 1.2145x over previous
//
#include <hip/hip_runtime.h>
#include <cstdint>

#define TB 2048     // T
#define DIM 2560    // D
#define NQ 8
#define NKV 4
#define HDIM 256
#define WIN 1024
#define KMASK -2.3819763e+38f

using f32x4 = __attribute__((ext_vector_type(4))) float;
using s16x8 = __attribute__((ext_vector_type(8))) short;
using u16x4 = __attribute__((ext_vector_type(4))) unsigned short;

__device__ __forceinline__ unsigned short f2bf(float f) {
  uint32_t x = __builtin_bit_cast(uint32_t, f);
  x += 0x7FFFu + ((x >> 16) & 1u);
  return (unsigned short)(x >> 16);
}

// ---------- pack W1: 16 heads of (DIM x HDIM) f32 -> W1[c][d] bf16 (c = head*256+h) ----------
__global__ __launch_bounds__(256) void k_packw1(const float* __restrict__ q_w,
                                                const float* __restrict__ kv_w,
                                                unsigned short* __restrict__ W1) {
  __shared__ float tile[32][33];
  const int hd = blockIdx.z;  // 0..7 q heads, 8..11 k heads, 12..15 v heads
  const float* src = (hd < 8) ? (q_w + (size_t)hd * DIM * HDIM)
                              : (kv_w + (size_t)(hd - 8) * DIM * HDIM);
  unsigned short* dst = W1 + (size_t)hd * HDIM * DIM;
  const int c0 = blockIdx.x * 32, r0 = blockIdx.y * 32;  // c over HDIM, r over DIM
  const int tx = threadIdx.x & 31, ty = threadIdx.x >> 5;
#pragma unroll
  for (int i = 0; i < 32; i += 8)
    tile[ty + i][tx] = src[(size_t)(r0 + ty + i) * HDIM + c0 + tx];
  __syncthreads();
#pragma unroll
  for (int i = 0; i < 32; i += 8)
    dst[(size_t)(c0 + ty + i) * DIM + r0 + tx] = f2bf(tile[tx][ty + i]);
}

// ---------- generic transpose f32 (RxC) -> bf16 (CxR) ----------
__global__ __launch_bounds__(256) void k_tconv(const float* __restrict__ src,
                                               unsigned short* __restrict__ dst,
                                               int R, int C) {
  __shared__ float tile[32][33];
  const int c0 = blockIdx.x * 32, r0 = blockIdx.y * 32;
  const int tx = threadIdx.x & 31, ty = threadIdx.x >> 5;
#pragma unroll
  for (int i = 0; i < 32; i += 8)
    tile[ty + i][tx] = src[(size_t)(r0 + ty + i) * C + c0 + tx];
  __syncthreads();
#pragma unroll
  for (int i = 0; i < 32; i += 8)
    dst[(size_t)(c0 + ty + i) * R + r0 + tx] = f2bf(tile[tx][ty + i]);
}

// ---------- f32 -> bf16 elementwise (4/thread) ----------
__global__ __launch_bounds__(256) void k_cvt(const float* __restrict__ src,
                                             unsigned short* __restrict__ dst, int n4) {
  int i = blockIdx.x * 256 + threadIdx.x;
  if (i < n4) {
    f32x4 v = *(const f32x4*)&src[(size_t)i * 4];
    u16x4 o;
#pragma unroll
    for (int j = 0; j < 4; ++j) o[j] = f2bf(v[j]);
    *(u16x4*)&dst[(size_t)i * 4] = o;
  }
}

// ---------- 256x256 tile bf16 GEMM, 2-dbuf stage-ahead counted-vmcnt pipeline ----------
// C[M][Nc] = A[M][Kd] * Bw[Nc][Kd]^T.  512 threads = 8 waves (2M x 4N), per-wave 128x64.
// LDS 128 KB: dbuf[2] x (A 256x64 + B 256x64) bf16, XOR-swizzled rows (proven conflict-free).
// Per iter: issue 8 gload_lds for tile t+1, vmcnt(8) confirms tile t, barrier, 24 ds_read_b128,
// 64 MFMA, barrier. 2-D XCD partition: each XCD owns a 4m x nxl region.
__global__ __launch_bounds__(512, 2) void k_gemm(const unsigned short* __restrict__ A,
                                                 const unsigned short* __restrict__ Bw,
                                                 float* __restrict__ Cc,
                                                 int Nc, int Kd, int nxl) {
  __shared__ unsigned short shA[2][256 * 64];
  __shared__ unsigned short shB[2][256 * 64];
  const int tid = threadIdx.x, w = tid >> 6, l = tid & 63;
  const int xcd = blockIdx.x & 7, loc = blockIdx.x >> 3;
  const int m0 = ((xcd >> 1) * 4 + loc / nxl) * 256;
  const int n0 = ((xcd & 1) * nxl + loc % nxl) * 256;

  const int srow = l >> 3;                      // 0..7
  const int sw_colb = (((l & 7) ^ srow) << 4);  // inverse-swizzled source col (bytes)
  const int wrow = w * 8;
  const int NT = Kd >> 6;

#define GSTAGE(buf, t)                                                                      \
  {                                                                                         \
    const size_t kt = (size_t)(t) << 6;                                                     \
    _Pragma("unroll") for (int r = 0; r < 4; ++r) {                                         \
      const char* src = (const char*)A + ((size_t)(m0 + r * 64 + wrow + srow) * Kd + kt) * 2 + sw_colb; \
      __builtin_amdgcn_global_load_lds(                                                     \
          (__attribute__((address_space(1))) void*)src,                                     \
          (__attribute__((address_space(3))) void*)((char*)&shA[buf][0] + r * 8192 + w * 1024), \
          16, 0, 0);                                                                        \
    }                                                                                       \
    _Pragma("unroll") for (int r = 0; r < 4; ++r) {                                         \
      const char* src = (const char*)Bw + ((size_t)(n0 + r * 64 + wrow + srow) * Kd + kt) * 2 + sw_colb; \
      __builtin_amdgcn_global_load_lds(                                                     \
          (__attribute__((address_space(1))) void*)src,                                     \
          (__attribute__((address_space(3))) void*)((char*)&shB[buf][0] + r * 8192 + w * 1024), \
          16, 0, 0);                                                                        \
    }                                                                                       \
  }

  const int wm = w >> 2, wn = w & 3;  // 2M x 4N wave grid
  const int lr = l & 15, lg = l >> 4;
  f32x4 acc[8][4] = {};

  GSTAGE(0, 0);

  for (int t = 0; t < NT; ++t) {
    const int buf = t & 1;
    if (t + 1 < NT) {
      GSTAGE(buf ^ 1, t + 1);
      asm volatile("s_waitcnt vmcnt(8)" ::: "memory");  // tile t resident; t+1 in flight
    } else {
      asm volatile("s_waitcnt vmcnt(0)" ::: "memory");
    }
    __builtin_amdgcn_s_barrier();

    const char* sa = (const char*)&shA[buf][0];
    const char* sb = (const char*)&shB[buf][0];
#pragma unroll
    for (int kk = 0; kk < 2; ++kk) {
      const int cb = kk * 64 + lg * 16;
      const int cbx = cb ^ ((lr & 7) << 4);  // row&7 == lr&7 for all frag rows
      s16x8 af[8], bfr[4];
#pragma unroll
      for (int mi = 0; mi < 8; ++mi)
        af[mi] = *(const s16x8*)(sa + (wm * 128 + mi * 16 + lr) * 128 + cbx);
#pragma unroll
      for (int ni = 0; ni < 4; ++ni)
        bfr[ni] = *(const s16x8*)(sb + (wn * 64 + ni * 16 + lr) * 128 + cbx);
      __builtin_amdgcn_s_setprio(1);
#pragma unroll
      for (int mi = 0; mi < 8; ++mi)
#pragma unroll
        for (int ni = 0; ni < 4; ++ni)
          acc[mi][ni] = __builtin_amdgcn_mfma_f32_16x16x32_bf16(af[mi], bfr[ni], acc[mi][ni], 0, 0, 0);
      __builtin_amdgcn_s_setprio(0);
    }
    __builtin_amdgcn_s_barrier();  // protect dbuf reuse by next iter's stage
  }
#undef GSTAGE

#pragma unroll
  for (int mi = 0; mi < 8; ++mi)
#pragma unroll
    for (int ni = 0; ni < 4; ++ni) {
      size_t base = (size_t)(m0 + wm * 128 + mi * 16 + lg * 4) * Nc + (n0 + wn * 64 + ni * 16 + lr);
#pragma unroll
      for (int i = 0; i < 4; ++i)
        Cc[base + (size_t)i * Nc] = acc[mi][ni][i];
    }
}

// ---------- RMSNorm + RoPE for q/k channels of Y; writes bf16 Q[B][NQ][T][H], K[B][NKV][T][H] ----------
__global__ __launch_bounds__(256) void k_normrope(const float* __restrict__ Y,
                                                  const float* __restrict__ qsc,
                                                  const float* __restrict__ ksc,
                                                  const int* __restrict__ pos,
                                                  unsigned short* __restrict__ Q,
                                                  unsigned short* __restrict__ Kb) {
  __shared__ float s_sin[128], s_cos[128];
  const int bt = blockIdx.x;
  const int b = bt >> 11, t = bt & (TB - 1);
  const int tid = threadIdx.x;
  float p = (float)pos[bt];
  if (tid < 128) {
    float fr = (float)tid * (1.0f / 128.0f);
    float inv_ts = __expf(fr * -9.210340371976184f);  // 10000^-fr
    float ang = p * inv_ts;
    float sv, cv;
    sincosf(ang, &sv, &cv);
    s_sin[tid] = sv;
    s_cos[tid] = cv;
  }
  __syncthreads();
  const int w = tid >> 6, l = tid & 63;
  const int jj0 = (l & 31) * 4;
  for (int sidx = w; sidx < 12; sidx += 4) {  // 0..7 q heads, 8..11 k heads
    const float* src = Y + (size_t)bt * 4096 + sidx * 256;
    f32x4 v = *(const f32x4*)&src[l * 4];
    float ss = v[0] * v[0] + v[1] * v[1] + v[2] * v[2] + v[3] * v[3];
#pragma unroll
    for (int d = 1; d < 64; d <<= 1) ss += __shfl_xor(ss, d);
    float rs = rsqrtf(ss * (1.0f / 256.0f) + 1e-6f);
    const float* scp = (sidx < 8) ? qsc : ksc;
    float nv[4], res[4];
#pragma unroll
    for (int j = 0; j < 4; ++j) nv[j] = v[j] * rs * (1.0f + scp[l * 4 + j]);
#pragma unroll
    for (int j = 0; j < 4; ++j) {
      float o = __shfl_xor(nv[j], 32);
      float sn = s_sin[jj0 + j], cs = s_cos[jj0 + j];
      res[j] = (l < 32) ? (nv[j] * cs - o * sn) : (nv[j] * cs + o * sn);
    }
    float qs = (sidx < 8) ? 0.0625f : 1.0f;  // H^-0.5 = 1/16 folded into q
    u16x4 ob;
#pragma unroll
    for (int j = 0; j < 4; ++j) ob[j] = f2bf(res[j] * qs);
    if (sidx < 8) {
      size_t di = ((size_t)(b * NQ + sidx) * TB + t) * HDIM + l * 4;
      *(u16x4*)&Q[di] = ob;
    } else {
      size_t di = ((size_t)(b * NKV + (sidx - 8)) * TB + t) * HDIM + l * 4;
      *(u16x4*)&Kb[di] = ob;
    }
  }
}

// ---------- transpose v channels of Y -> VT[B][NKV][H][T] bf16 ----------
__global__ __launch_bounds__(256) void k_vtrans(const float* __restrict__ Y,
                                                unsigned short* __restrict__ VT) {
  __shared__ float tile[64][65];
  const int t0 = blockIdx.x * 64, h0 = blockIdx.y * 64;
  const int z = blockIdx.z;  // b*4+kh
  const int bq = z >> 2, kh = z & 3;
  const int tid = threadIdx.x;
#pragma unroll
  for (int rep = 0; rep < 16; ++rep) {
    int idx = rep * 256 + tid;
    int tr = idx >> 6, hc = idx & 63;
    tile[tr][hc] = Y[(size_t)(bq * TB + t0 + tr) * 4096 + 3072 + kh * 256 + h0 + hc];
  }
  __syncthreads();
#pragma unroll
  for (int rep = 0; rep < 16; ++rep) {
    int idx = rep * 256 + tid;
    int hr = idx >> 6, tc = idx & 63;
    VT[((size_t)z * 256 + h0 + hr) * TB + t0 + tc] = f2bf(tile[tc][hr]);
  }
}

// ---------- flash attention: LDS-staged K/V tiles, double-buffered, 4 waves share ----------
__global__ __launch_bounds__(256, 2) void k_attn(const unsigned short* __restrict__ Q,
                                                 const unsigned short* __restrict__ Kb,
                                                 const unsigned short* __restrict__ VT,
                                                 unsigned short* __restrict__ ENC) {
  __shared__ unsigned short shK[2][32 * 256];  // [s-row][h], 512B rows, XOR-swizzled
  __shared__ unsigned short shV[2][256 * 32];  // [h-row][s], 64B rows, natural layout
  __shared__ unsigned short Pb[4][512];
  const int tid = threadIdx.x, w = tid >> 6, l = tid & 63;
  const int bn = blockIdx.y;
  const int b = bn >> 3, n = bn & 7, kh = n >> 1;
  const int t0b = blockIdx.x * 64;
  const int t0 = t0b + w * 16;
  const int lr = l & 15, lg = l >> 4;
  const unsigned short* qp = Q + ((size_t)bn * TB + t0) * HDIM;
  const char* kbase = (const char*)(Kb + ((size_t)(b * NKV + kh) * TB) * HDIM);
  const char* vbase = (const char*)(VT + ((size_t)(b * NKV + kh) * HDIM) * TB);

  s16x8 aq[8];
#pragma unroll
  for (int kk = 0; kk < 8; ++kk)
    aq[kk] = *(const s16x8*)&qp[lr * HDIM + kk * 32 + lg * 8];

  f32x4 o[16] = {};
  float mrow[4], lsum[4];
#pragma unroll
  for (int i = 0; i < 4; ++i) { mrow[i] = -__builtin_inff(); lsum[i] = 0.f; }

  int lo = t0b - (WIN - 1);
  if (lo < 0) lo = 0;
  lo &= ~31;
  const int nsteps = (t0b + 32 - lo) / 32 + 1;

  // stage K-tile (32x256, source-swizzled) + V-tile (256x32) for key block s0
  const int k_row = (w << 1) + (l >> 5);           // within 8-row group per issue
  const int k_colb = (l & 31) * 16;                // byte col 0..496
  const int v_row = (w << 4) + (l >> 2);           // within 64-row group per issue
  const int v_colb = (l & 3) * 16;                 // byte col 0..48
#define STAGE(buf, s0)                                                                       \
  {                                                                                          \
    _Pragma("unroll") for (int r = 0; r < 4; ++r) {                                          \
      int row = r * 8 + k_row;                                                               \
      int scol = k_colb ^ ((row & 7) << 4);                                                  \
      const char* src = kbase + (size_t)((s0) + row) * 512 + scol;                           \
      __builtin_amdgcn_global_load_lds(                                                      \
          (__attribute__((address_space(1))) void*)src,                                      \
          (__attribute__((address_space(3))) void*)((char*)&shK[buf][0] + r * 4096 + w * 1024), \
          16, 0, 0);                                                                         \
    }                                                                                        \
    _Pragma("unroll") for (int r = 0; r < 4; ++r) {                                          \
      int row = r * 64 + v_row;                                                              \
      const char* src = vbase + (size_t)row * (TB * 2) + (size_t)(s0) * 2 + v_colb;          \
      __builtin_amdgcn_global_load_lds(                                                      \
          (__attribute__((address_space(1))) void*)src,                                      \
          (__attribute__((address_space(3))) void*)((char*)&shV[buf][0] + r * 4096 + w * 1024), \
          16, 0, 0);                                                                         \
    }                                                                                        \
  }

  STAGE(0, lo);
  __syncthreads();

  for (int step = 0; step < nsteps; ++step) {
    const int s0 = lo + step * 32;
    const int buf = step & 1;
    if (step + 1 < nsteps) STAGE(buf ^ 1, s0 + 32);

    const bool active = (s0 <= t0 + 15) && (s0 + 31 >= t0 - (WIN - 1));
    if (active) {
      // QK^T from LDS (swizzled read)
      f32x4 sacc[2] = {};
      const char* kt = (const char*)&shK[buf][0];
      const int swz = (lr & 7) << 4;
#pragma unroll
      for (int cb = 0; cb < 2; ++cb) {
        const int rb = (cb * 16 + lr) * 512;
#pragma unroll
        for (int kk = 0; kk < 8; ++kk) {
          s16x8 bk = *(const s16x8*)(kt + rb + ((kk * 64 + lg * 16) ^ swz));
          sacc[cb] = __builtin_amdgcn_mfma_f32_16x16x32_bf16(aq[kk], bk, sacc[cb], 0, 0, 0);
        }
      }
      float r_[4], p0[4], p1[4];
#pragma unroll
      for (int i = 0; i < 4; ++i) {
        int trow = t0 + lg * 4 + i;
        int sA = s0 + lr, sB = s0 + 16 + lr;
        float svA = ((sA <= trow) && (trow - sA < WIN)) ? sacc[0][i] : KMASK;
        float svB = ((sB <= trow) && (trow - sB < WIN)) ? sacc[1][i] : KMASK;
        float mx = fmaxf(svA, svB);
#pragma unroll
        for (int d = 1; d < 16; d <<= 1) mx = fmaxf(mx, __shfl_xor(mx, d));
        float mnew = fmaxf(mrow[i], mx);
        float r = __expf(mrow[i] - mnew);
        float pa = __expf(svA - mnew);
        float pb = __expf(svB - mnew);
        float bs = pa + pb;
#pragma unroll
        for (int d = 1; d < 16; d <<= 1) bs += __shfl_xor(bs, d);
        lsum[i] = lsum[i] * r + bs;
        mrow[i] = mnew;
        r_[i] = r; p0[i] = pa; p1[i] = pb;
      }
#pragma unroll
      for (int hb = 0; hb < 16; ++hb)
#pragma unroll
        for (int i = 0; i < 4; ++i) o[hb][i] *= r_[i];
      // C-layout -> A-layout via per-wave LDS buffer
#pragma unroll
      for (int i = 0; i < 4; ++i) {
        int row = lg * 4 + i;
        Pb[w][row * 32 + lr] = f2bf(p0[i]);
        Pb[w][row * 32 + 16 + lr] = f2bf(p1[i]);
      }
      asm volatile("s_waitcnt lgkmcnt(0)" ::: "memory");
      s16x8 pfrag = *(const s16x8*)&Pb[w][lr * 32 + lg * 8];
      // PV from LDS V-tile
      const char* vt = (const char*)&shV[buf][0];
#pragma unroll
      for (int hb = 0; hb < 16; ++hb) {
        s16x8 vb = *(const s16x8*)(vt + (hb * 16 + lr) * 64 + lg * 16);
        o[hb] = __builtin_amdgcn_mfma_f32_16x16x32_bf16(pfrag, vb, o[hb], 0, 0, 0);
      }
    }
    __syncthreads();
  }
#undef STAGE

#pragma unroll
  for (int i = 0; i < 4; ++i) {
    int trow = t0 + lg * 4 + i;
    float inv = 1.0f / lsum[i];
    size_t rb = (size_t)(b * TB + trow) * 2048 + n * HDIM;
#pragma unroll
    for (int hb = 0; hb < 16; ++hb)
      ENC[rb + hb * 16 + lr] = f2bf(o[hb][i] * inv);
  }
}

extern "C" void kernel_launch(void* const* d_in, const int* in_sizes, int n_in,
                              void* d_out, int out_size, void* d_ws, size_t ws_size,
                              hipStream_t stream) {
  (void)in_sizes; (void)n_in; (void)out_size; (void)ws_size;
  const float* x = (const float*)d_in[0];
  const float* q_w = (const float*)d_in[1];
  const float* kv_w = (const float*)d_in[2];
  const float* qsc = (const float*)d_in[3];
  const float* ksc = (const float*)d_in[4];
  const float* out_w = (const float*)d_in[5];
  const int* pos = (const int*)d_in[6];
  float* out = (float*)d_out;

  char* ws = (char*)d_ws;
  unsigned short* W1 = (unsigned short*)(ws);              // 4096x2560 bf16 (20.97 MB)
  unsigned short* W3 = (unsigned short*)(ws + 20971520);   // 2560x2048 bf16 (10.49 MB)
  unsigned short* XB = (unsigned short*)(ws + 31457280);   // 4096x2560 bf16 (20.97 MB)
  float* Y = (float*)(ws + 52428800);                      // 4096x4096 f32  (67.1 MB)
  unsigned short* KB = (unsigned short*)(ws + 119537664);  // 2x4x2048x256 bf16 (8.39 MB)
  unsigned short* VT = (unsigned short*)(ws + 127926272);  // 2x4x256x2048 bf16 (8.39 MB)
  unsigned short* Qb = XB;                                 // reuse XB after GEMM1
  unsigned short* ENC = (unsigned short*)(ws + 52428800);  // reuse Y after norm/vtrans

  k_packw1<<<dim3(8, 80, 16), 256, 0, stream>>>(q_w, kv_w, W1);
  k_tconv<<<dim3(80, 64), 256, 0, stream>>>(out_w, W3, 2048, DIM);
  k_cvt<<<dim3(10240), 256, 0, stream>>>(x, XB, 2621440);
  // GEMM1: M=4096 (16 m-tiles), N=4096 (16 n-tiles) -> 256 blocks, XCD region 4m x 8n
  k_gemm<<<dim3(256), 512, 0, stream>>>(XB, W1, Y, 4096, DIM, 8);
  k_normrope<<<dim3(4096), 256, 0, stream>>>(Y, qsc, ksc, pos, Qb, KB);
  k_vtrans<<<dim3(32, 4, 8), 256, 0, stream>>>(Y, VT);
  k_attn<<<dim3(32, 16), 256, 0, stream>>>(Qb, KB, VT, ENC);
  // GEMM3: M=4096 (16 m-tiles), N=2560 (10 n-tiles) -> 160 blocks, XCD region 4m x 5n
  k_gemm<<<dim3(160), 512, 0, stream>>>(ENC, W3, out, DIM, 2048, 5);
}

// Round 5
// 296.497 us; speedup vs baseline: 1.2183x; 1.0031x over previous
//
#include <hip/hip_runtime.h>
#include <cstdint>

#define TB 2048     // T
#define DIM 2560    // D
#define NQ 8
#define NKV 4
#define HDIM 256
#define WIN 1024
#define KMASK -2.3819763e+38f

using f32x4 = __attribute__((ext_vector_type(4))) float;
using s16x8 = __attribute__((ext_vector_type(8))) short;
using u16x4 = __attribute__((ext_vector_type(4))) unsigned short;

__device__ __forceinline__ unsigned short f2bf(float f) {
  uint32_t x = __builtin_bit_cast(uint32_t, f);
  x += 0x7FFFu + ((x >> 16) & 1u);
  return (unsigned short)(x >> 16);
}

// ---------- pack W1: 16 heads of (DIM x HDIM) f32 -> W1[c][d] bf16 (c = head*256+h) ----------
__global__ __launch_bounds__(256) void k_packw1(const float* __restrict__ q_w,
                                                const float* __restrict__ kv_w,
                                                unsigned short* __restrict__ W1) {
  __shared__ float tile[32][33];
  const int hd = blockIdx.z;  // 0..7 q heads, 8..11 k heads, 12..15 v heads
  const float* src = (hd < 8) ? (q_w + (size_t)hd * DIM * HDIM)
                              : (kv_w + (size_t)(hd - 8) * DIM * HDIM);
  unsigned short* dst = W1 + (size_t)hd * HDIM * DIM;
  const int c0 = blockIdx.x * 32, r0 = blockIdx.y * 32;  // c over HDIM, r over DIM
  const int tx = threadIdx.x & 31, ty = threadIdx.x >> 5;
#pragma unroll
  for (int i = 0; i < 32; i += 8)
    tile[ty + i][tx] = src[(size_t)(r0 + ty + i) * HDIM + c0 + tx];
  __syncthreads();
#pragma unroll
  for (int i = 0; i < 32; i += 8)
    dst[(size_t)(c0 + ty + i) * DIM + r0 + tx] = f2bf(tile[tx][ty + i]);
}

// ---------- generic transpose f32 (RxC) -> bf16 (CxR) ----------
__global__ __launch_bounds__(256) void k_tconv(const float* __restrict__ src,
                                               unsigned short* __restrict__ dst,
                                               int R, int C) {
  __shared__ float tile[32][33];
  const int c0 = blockIdx.x * 32, r0 = blockIdx.y * 32;
  const int tx = threadIdx.x & 31, ty = threadIdx.x >> 5;
#pragma unroll
  for (int i = 0; i < 32; i += 8)
    tile[ty + i][tx] = src[(size_t)(r0 + ty + i) * C + c0 + tx];
  __syncthreads();
#pragma unroll
  for (int i = 0; i < 32; i += 8)
    dst[(size_t)(c0 + ty + i) * R + r0 + tx] = f2bf(tile[tx][ty + i]);
}

// ---------- f32 -> bf16 elementwise (4/thread) ----------
__global__ __launch_bounds__(256) void k_cvt(const float* __restrict__ src,
                                             unsigned short* __restrict__ dst, int n4) {
  int i = blockIdx.x * 256 + threadIdx.x;
  if (i < n4) {
    f32x4 v = *(const f32x4*)&src[(size_t)i * 4];
    u16x4 o;
#pragma unroll
    for (int j = 0; j < 4; ++j) o[j] = f2bf(v[j]);
    *(u16x4*)&dst[(size_t)i * 4] = o;
  }
}

// ---------- 256x256 tile bf16 GEMM, 2-dbuf stage-ahead counted-vmcnt pipeline ----------
__global__ __launch_bounds__(512, 2) void k_gemm(const unsigned short* __restrict__ A,
                                                 const unsigned short* __restrict__ Bw,
                                                 float* __restrict__ Cc,
                                                 int Nc, int Kd, int nxl) {
  __shared__ unsigned short shA[2][256 * 64];
  __shared__ unsigned short shB[2][256 * 64];
  const int tid = threadIdx.x, w = tid >> 6, l = tid & 63;
  const int xcd = blockIdx.x & 7, loc = blockIdx.x >> 3;
  const int m0 = ((xcd >> 1) * 4 + loc / nxl) * 256;
  const int n0 = ((xcd & 1) * nxl + loc % nxl) * 256;

  const int srow = l >> 3;                      // 0..7
  const int sw_colb = (((l & 7) ^ srow) << 4);  // inverse-swizzled source col (bytes)
  const int wrow = w * 8;
  const int NT = Kd >> 6;

#define GSTAGE(buf, t)                                                                      \
  {                                                                                         \
    const size_t kt = (size_t)(t) << 6;                                                     \
    _Pragma("unroll") for (int r = 0; r < 4; ++r) {                                         \
      const char* src = (const char*)A + ((size_t)(m0 + r * 64 + wrow + srow) * Kd + kt) * 2 + sw_colb; \
      __builtin_amdgcn_global_load_lds(                                                     \
          (__attribute__((address_space(1))) void*)src,                                     \
          (__attribute__((address_space(3))) void*)((char*)&shA[buf][0] + r * 8192 + w * 1024), \
          16, 0, 0);                                                                        \
    }                                                                                       \
    _Pragma("unroll") for (int r = 0; r < 4; ++r) {                                         \
      const char* src = (const char*)Bw + ((size_t)(n0 + r * 64 + wrow + srow) * Kd + kt) * 2 + sw_colb; \
      __builtin_amdgcn_global_load_lds(                                                     \
          (__attribute__((address_space(1))) void*)src,                                     \
          (__attribute__((address_space(3))) void*)((char*)&shB[buf][0] + r * 8192 + w * 1024), \
          16, 0, 0);                                                                        \
    }                                                                                       \
  }

  const int wm = w >> 2, wn = w & 3;  // 2M x 4N wave grid
  const int lr = l & 15, lg = l >> 4;
  f32x4 acc[8][4] = {};

  GSTAGE(0, 0);

  for (int t = 0; t < NT; ++t) {
    const int buf = t & 1;
    if (t + 1 < NT) {
      GSTAGE(buf ^ 1, t + 1);
      asm volatile("s_waitcnt vmcnt(8)" ::: "memory");  // tile t resident; t+1 in flight
    } else {
      asm volatile("s_waitcnt vmcnt(0)" ::: "memory");
    }
    __builtin_amdgcn_s_barrier();

    const char* sa = (const char*)&shA[buf][0];
    const char* sb = (const char*)&shB[buf][0];
#pragma unroll
    for (int kk = 0; kk < 2; ++kk) {
      const int cb = kk * 64 + lg * 16;
      const int cbx = cb ^ ((lr & 7) << 4);  // row&7 == lr&7 for all frag rows
      s16x8 af[8], bfr[4];
#pragma unroll
      for (int mi = 0; mi < 8; ++mi)
        af[mi] = *(const s16x8*)(sa + (wm * 128 + mi * 16 + lr) * 128 + cbx);
#pragma unroll
      for (int ni = 0; ni < 4; ++ni)
        bfr[ni] = *(const s16x8*)(sb + (wn * 64 + ni * 16 + lr) * 128 + cbx);
      __builtin_amdgcn_s_setprio(1);
#pragma unroll
      for (int mi = 0; mi < 8; ++mi)
#pragma unroll
        for (int ni = 0; ni < 4; ++ni)
          acc[mi][ni] = __builtin_amdgcn_mfma_f32_16x16x32_bf16(af[mi], bfr[ni], acc[mi][ni], 0, 0, 0);
      __builtin_amdgcn_s_setprio(0);
    }
    __builtin_amdgcn_s_barrier();  // protect dbuf reuse by next iter's stage
  }
#undef GSTAGE

#pragma unroll
  for (int mi = 0; mi < 8; ++mi)
#pragma unroll
    for (int ni = 0; ni < 4; ++ni) {
      size_t base = (size_t)(m0 + wm * 128 + mi * 16 + lg * 4) * Nc + (n0 + wn * 64 + ni * 16 + lr);
#pragma unroll
      for (int i = 0; i < 4; ++i)
        Cc[base + (size_t)i * Nc] = acc[mi][ni][i];
    }
}

// ---------- RMSNorm + RoPE for q/k channels of Y; writes bf16 Q[B][NQ][T][H], K[B][NKV][T][H] ----------
__global__ __launch_bounds__(256) void k_normrope(const float* __restrict__ Y,
                                                  const float* __restrict__ qsc,
                                                  const float* __restrict__ ksc,
                                                  const int* __restrict__ pos,
                                                  unsigned short* __restrict__ Q,
                                                  unsigned short* __restrict__ Kb) {
  __shared__ float s_sin[128], s_cos[128];
  const int bt = blockIdx.x;
  const int b = bt >> 11, t = bt & (TB - 1);
  const int tid = threadIdx.x;
  float p = (float)pos[bt];
  if (tid < 128) {
    float fr = (float)tid * (1.0f / 128.0f);
    float inv_ts = __expf(fr * -9.210340371976184f);  // 10000^-fr
    float ang = p * inv_ts;
    float sv, cv;
    sincosf(ang, &sv, &cv);
    s_sin[tid] = sv;
    s_cos[tid] = cv;
  }
  __syncthreads();
  const int w = tid >> 6, l = tid & 63;
  const int jj0 = (l & 31) * 4;
  for (int sidx = w; sidx < 12; sidx += 4) {  // 0..7 q heads, 8..11 k heads
    const float* src = Y + (size_t)bt * 4096 + sidx * 256;
    f32x4 v = *(const f32x4*)&src[l * 4];
    float ss = v[0] * v[0] + v[1] * v[1] + v[2] * v[2] + v[3] * v[3];
#pragma unroll
    for (int d = 1; d < 64; d <<= 1) ss += __shfl_xor(ss, d);
    float rs = rsqrtf(ss * (1.0f / 256.0f) + 1e-6f);
    const float* scp = (sidx < 8) ? qsc : ksc;
    float nv[4], res[4];
#pragma unroll
    for (int j = 0; j < 4; ++j) nv[j] = v[j] * rs * (1.0f + scp[l * 4 + j]);
#pragma unroll
    for (int j = 0; j < 4; ++j) {
      float o = __shfl_xor(nv[j], 32);
      float sn = s_sin[jj0 + j], cs = s_cos[jj0 + j];
      res[j] = (l < 32) ? (nv[j] * cs - o * sn) : (nv[j] * cs + o * sn);
    }
    float qs = (sidx < 8) ? 0.0625f : 1.0f;  // H^-0.5 = 1/16 folded into q
    u16x4 ob;
#pragma unroll
    for (int j = 0; j < 4; ++j) ob[j] = f2bf(res[j] * qs);
    if (sidx < 8) {
      size_t di = ((size_t)(b * NQ + sidx) * TB + t) * HDIM + l * 4;
      *(u16x4*)&Q[di] = ob;
    } else {
      size_t di = ((size_t)(b * NKV + (sidx - 8)) * TB + t) * HDIM + l * 4;
      *(u16x4*)&Kb[di] = ob;
    }
  }
}

// ---------- transpose v channels of Y -> VT[B][NKV][H][T] bf16 ----------
__global__ __launch_bounds__(256) void k_vtrans(const float* __restrict__ Y,
                                                unsigned short* __restrict__ VT) {
  __shared__ float tile[64][65];
  const int t0 = blockIdx.x * 64, h0 = blockIdx.y * 64;
  const int z = blockIdx.z;  // b*4+kh
  const int bq = z >> 2, kh = z & 3;
  const int tid = threadIdx.x;
#pragma unroll
  for (int rep = 0; rep < 16; ++rep) {
    int idx = rep * 256 + tid;
    int tr = idx >> 6, hc = idx & 63;
    tile[tr][hc] = Y[(size_t)(bq * TB + t0 + tr) * 4096 + 3072 + kh * 256 + h0 + hc];
  }
  __syncthreads();
#pragma unroll
  for (int rep = 0; rep < 16; ++rep) {
    int idx = rep * 256 + tid;
    int hr = idx >> 6, tc = idx & 63;
    VT[((size_t)z * 256 + h0 + hr) * TB + t0 + tc] = f2bf(tile[tc][hr]);
  }
}

// ---------- flash attention: LDS-staged K/V, defer-rescale, uniform-mask skip ----------
__global__ __launch_bounds__(256, 2) void k_attn(const unsigned short* __restrict__ Q,
                                                 const unsigned short* __restrict__ Kb,
                                                 const unsigned short* __restrict__ VT,
                                                 unsigned short* __restrict__ ENC) {
  __shared__ unsigned short shK[2][32 * 256];  // [s-row][h], 512B rows, XOR-swizzled
  __shared__ unsigned short shV[2][256 * 32];  // [h-row][s], 64B rows, natural layout
  __shared__ unsigned short Pb[4][16 * 40];    // 80B rows: padded, conflict-free
  const int tid = threadIdx.x, w = tid >> 6, l = tid & 63;
  const int bn = blockIdx.y;
  const int b = bn >> 3, n = bn & 7, kh = n >> 1;
  const int t0b = blockIdx.x * 64;
  const int t0 = t0b + w * 16;
  const int lr = l & 15, lg = l >> 4;
  const unsigned short* qp = Q + ((size_t)bn * TB + t0) * HDIM;
  const char* kbase = (const char*)(Kb + ((size_t)(b * NKV + kh) * TB) * HDIM);
  const char* vbase = (const char*)(VT + ((size_t)(b * NKV + kh) * HDIM) * TB);

  s16x8 aq[8];
#pragma unroll
  for (int kk = 0; kk < 8; ++kk)
    aq[kk] = *(const s16x8*)&qp[lr * HDIM + kk * 32 + lg * 8];

  f32x4 o[16] = {};
  float mrow[4], lsum[4];
#pragma unroll
  for (int i = 0; i < 4; ++i) { mrow[i] = -__builtin_inff(); lsum[i] = 0.f; }

  int lo = t0b - (WIN - 1);
  if (lo < 0) lo = 0;
  lo &= ~31;
  const int nsteps = (t0b + 32 - lo) / 32 + 1;

  // stage K-tile (32x256, source-swizzled) + V-tile (256x32) for key block s0
  const int k_row = (w << 1) + (l >> 5);           // within 8-row group per issue
  const int k_colb = (l & 31) * 16;                // byte col 0..496
  const int v_row = (w << 4) + (l >> 2);           // within 64-row group per issue
  const int v_colb = (l & 3) * 16;                 // byte col 0..48
#define STAGE(buf, s0)                                                                       \
  {                                                                                          \
    _Pragma("unroll") for (int r = 0; r < 4; ++r) {                                          \
      int row = r * 8 + k_row;                                                               \
      int scol = k_colb ^ ((row & 7) << 4);                                                  \
      const char* src = kbase + (size_t)((s0) + row) * 512 + scol;                           \
      __builtin_amdgcn_global_load_lds(                                                      \
          (__attribute__((address_space(1))) void*)src,                                      \
          (__attribute__((address_space(3))) void*)((char*)&shK[buf][0] + r * 4096 + w * 1024), \
          16, 0, 0);                                                                         \
    }                                                                                        \
    _Pragma("unroll") for (int r = 0; r < 4; ++r) {                                          \
      int row = r * 64 + v_row;                                                              \
      const char* src = vbase + (size_t)row * (TB * 2) + (size_t)(s0) * 2 + v_colb;          \
      __builtin_amdgcn_global_load_lds(                                                      \
          (__attribute__((address_space(1))) void*)src,                                      \
          (__attribute__((address_space(3))) void*)((char*)&shV[buf][0] + r * 4096 + w * 1024), \
          16, 0, 0);                                                                         \
    }                                                                                        \
  }

  STAGE(0, lo);
  __syncthreads();

  for (int step = 0; step < nsteps; ++step) {
    const int s0 = lo + step * 32;
    const int buf = step & 1;
    if (step + 1 < nsteps) STAGE(buf ^ 1, s0 + 32);

    const bool active = (s0 <= t0 + 15) && (s0 + 31 >= t0 - (WIN - 1));
    if (active) {
      // QK^T from LDS (swizzled read)
      f32x4 sacc[2] = {};
      const char* kt = (const char*)&shK[buf][0];
      const int swz = (lr & 7) << 4;
#pragma unroll
      for (int cb = 0; cb < 2; ++cb) {
        const int rb = (cb * 16 + lr) * 512;
        s16x8 bk[8];
#pragma unroll
        for (int kk = 0; kk < 8; ++kk)
          bk[kk] = *(const s16x8*)(kt + rb + ((kk * 64 + lg * 16) ^ swz));
        __builtin_amdgcn_s_setprio(1);
#pragma unroll
        for (int kk = 0; kk < 8; ++kk)
          sacc[cb] = __builtin_amdgcn_mfma_f32_16x16x32_bf16(aq[kk], bk[kk], sacc[cb], 0, 0, 0);
        __builtin_amdgcn_s_setprio(0);
      }
      // mask (skipped for interior steps: wave-uniform branch)
      float svA_[4], svB_[4], pmax[4];
      const bool nomask = (s0 + 31 <= t0) && (s0 >= t0 - (WIN - 16));
      if (nomask) {
#pragma unroll
        for (int i = 0; i < 4; ++i) { svA_[i] = sacc[0][i]; svB_[i] = sacc[1][i]; }
      } else {
#pragma unroll
        for (int i = 0; i < 4; ++i) {
          int trow = t0 + lg * 4 + i;
          int sA = s0 + lr, sB = s0 + 16 + lr;
          svA_[i] = ((sA <= trow) && (trow - sA < WIN)) ? sacc[0][i] : KMASK;
          svB_[i] = ((sB <= trow) && (trow - sB < WIN)) ? sacc[1][i] : KMASK;
        }
      }
      // per-row max reduce
#pragma unroll
      for (int i = 0; i < 4; ++i) {
        float mx = fmaxf(svA_[i], svB_[i]);
#pragma unroll
        for (int d = 1; d < 16; d <<= 1) mx = fmaxf(mx, __shfl_xor(mx, d));
        pmax[i] = mx;
      }
      // defer-rescale: skip o/lsum rescale unless max grew past threshold (T13)
      bool ok = (pmax[0] <= mrow[0] + 8.f) && (pmax[1] <= mrow[1] + 8.f) &&
                (pmax[2] <= mrow[2] + 8.f) && (pmax[3] <= mrow[3] + 8.f);
      if (!__all(ok)) {
        float r_[4];
#pragma unroll
        for (int i = 0; i < 4; ++i) {
          float mnew = fmaxf(mrow[i], pmax[i]);
          r_[i] = __expf(mrow[i] - mnew);
          lsum[i] *= r_[i];
          mrow[i] = mnew;
        }
#pragma unroll
        for (int hb = 0; hb < 16; ++hb)
#pragma unroll
          for (int i = 0; i < 4; ++i) o[hb][i] *= r_[i];
      }
      // P = exp(S - m), row-sum, stash to LDS in A-layout
#pragma unroll
      for (int i = 0; i < 4; ++i) {
        float pa = __expf(svA_[i] - mrow[i]);
        float pb = __expf(svB_[i] - mrow[i]);
        float bs = pa + pb;
#pragma unroll
        for (int d = 1; d < 16; d <<= 1) bs += __shfl_xor(bs, d);
        lsum[i] += bs;
        int row = lg * 4 + i;
        Pb[w][row * 40 + lr] = f2bf(pa);
        Pb[w][row * 40 + 16 + lr] = f2bf(pb);
      }
      asm volatile("s_waitcnt lgkmcnt(0)" ::: "memory");
      s16x8 pfrag = *(const s16x8*)&Pb[w][lr * 40 + lg * 8];
      // PV from LDS V-tile
      const char* vt = (const char*)&shV[buf][0];
      s16x8 vb[16];
#pragma unroll
      for (int hb = 0; hb < 16; ++hb)
        vb[hb] = *(const s16x8*)(vt + (hb * 16 + lr) * 64 + lg * 16);
      __builtin_amdgcn_s_setprio(1);
#pragma unroll
      for (int hb = 0; hb < 16; ++hb)
        o[hb] = __builtin_amdgcn_mfma_f32_16x16x32_bf16(pfrag, vb[hb], o[hb], 0, 0, 0);
      __builtin_amdgcn_s_setprio(0);
    }
    __syncthreads();
  }
#undef STAGE

#pragma unroll
  for (int i = 0; i < 4; ++i) {
    int trow = t0 + lg * 4 + i;
    float inv = 1.0f / lsum[i];
    size_t rb = (size_t)(b * TB + trow) * 2048 + n * HDIM;
#pragma unroll
    for (int hb = 0; hb < 16; ++hb)
      ENC[rb + hb * 16 + lr] = f2bf(o[hb][i] * inv);
  }
}

extern "C" void kernel_launch(void* const* d_in, const int* in_sizes, int n_in,
                              void* d_out, int out_size, void* d_ws, size_t ws_size,
                              hipStream_t stream) {
  (void)in_sizes; (void)n_in; (void)out_size; (void)ws_size;
  const float* x = (const float*)d_in[0];
  const float* q_w = (const float*)d_in[1];
  const float* kv_w = (const float*)d_in[2];
  const float* qsc = (const float*)d_in[3];
  const float* ksc = (const float*)d_in[4];
  const float* out_w = (const float*)d_in[5];
  const int* pos = (const int*)d_in[6];
  float* out = (float*)d_out;

  char* ws = (char*)d_ws;
  unsigned short* W1 = (unsigned short*)(ws);              // 4096x2560 bf16 (20.97 MB)
  unsigned short* W3 = (unsigned short*)(ws + 20971520);   // 2560x2048 bf16 (10.49 MB)
  unsigned short* XB = (unsigned short*)(ws + 31457280);   // 4096x2560 bf16 (20.97 MB)
  float* Y = (float*)(ws + 52428800);                      // 4096x4096 f32  (67.1 MB)
  unsigned short* KB = (unsigned short*)(ws + 119537664);  // 2x4x2048x256 bf16 (8.39 MB)
  unsigned short* VT = (unsigned short*)(ws + 127926272);  // 2x4x256x2048 bf16 (8.39 MB)
  unsigned short* Qb = XB;                                 // reuse XB after GEMM1
  unsigned short* ENC = (unsigned short*)(ws + 52428800);  // reuse Y after norm/vtrans

  k_packw1<<<dim3(8, 80, 16), 256, 0, stream>>>(q_w, kv_w, W1);
  k_tconv<<<dim3(80, 64), 256, 0, stream>>>(out_w, W3, 2048, DIM);
  k_cvt<<<dim3(10240), 256, 0, stream>>>(x, XB, 2621440);
  // GEMM1: M=4096 (16 m-tiles), N=4096 (16 n-tiles) -> 256 blocks, XCD region 4m x 8n
  k_gemm<<<dim3(256), 512, 0, stream>>>(XB, W1, Y, 4096, DIM, 8);
  k_normrope<<<dim3(4096), 256, 0, stream>>>(Y, qsc, ksc, pos, Qb, KB);
  k_vtrans<<<dim3(32, 4, 8), 256, 0, stream>>>(Y, VT);
  k_attn<<<dim3(32, 16), 256, 0, stream>>>(Qb, KB, VT, ENC);
  // GEMM3: M=4096 (16 m-tiles), N=2560 (10 n-tiles) -> 160 blocks, XCD region 4m x 5n
  k_gemm<<<dim3(160), 512, 0, stream>>>(ENC, W3, out, DIM, 2048, 5);
}

// Round 6
// 272.408 us; speedup vs baseline: 1.3261x; 1.0884x over previous
//
#include <hip/hip_runtime.h>
#include <cstdint>

#define TB 2048     // T
#define DIM 2560    // D
#define NQ 8
#define NKV 4
#define HDIM 256
#define WIN 1024
#define KMASK -2.3819763e+38f

using f32x4 = __attribute__((ext_vector_type(4))) float;
using s16x8 = __attribute__((ext_vector_type(8))) short;
using u16x4 = __attribute__((ext_vector_type(4))) unsigned short;

__device__ __forceinline__ unsigned short f2bf(float f) {
  uint32_t x = __builtin_bit_cast(uint32_t, f);
  x += 0x7FFFu + ((x >> 16) & 1u);
  return (unsigned short)(x >> 16);
}

// ---------- pack W1: 16 heads of (DIM x HDIM) f32 -> W1[c][d] bf16 (c = head*256+h) ----------
__global__ __launch_bounds__(256) void k_packw1(const float* __restrict__ q_w,
                                                const float* __restrict__ kv_w,
                                                unsigned short* __restrict__ W1) {
  __shared__ float tile[32][33];
  const int hd = blockIdx.z;  // 0..7 q heads, 8..11 k heads, 12..15 v heads
  const float* src = (hd < 8) ? (q_w + (size_t)hd * DIM * HDIM)
                              : (kv_w + (size_t)(hd - 8) * DIM * HDIM);
  unsigned short* dst = W1 + (size_t)hd * HDIM * DIM;
  const int c0 = blockIdx.x * 32, r0 = blockIdx.y * 32;  // c over HDIM, r over DIM
  const int tx = threadIdx.x & 31, ty = threadIdx.x >> 5;
#pragma unroll
  for (int i = 0; i < 32; i += 8)
    tile[ty + i][tx] = src[(size_t)(r0 + ty + i) * HDIM + c0 + tx];
  __syncthreads();
#pragma unroll
  for (int i = 0; i < 32; i += 8)
    dst[(size_t)(c0 + ty + i) * DIM + r0 + tx] = f2bf(tile[tx][ty + i]);
}

// ---------- generic transpose f32 (RxC) -> bf16 (CxR) ----------
__global__ __launch_bounds__(256) void k_tconv(const float* __restrict__ src,
                                               unsigned short* __restrict__ dst,
                                               int R, int C) {
  __shared__ float tile[32][33];
  const int c0 = blockIdx.x * 32, r0 = blockIdx.y * 32;
  const int tx = threadIdx.x & 31, ty = threadIdx.x >> 5;
#pragma unroll
  for (int i = 0; i < 32; i += 8)
    tile[ty + i][tx] = src[(size_t)(r0 + ty + i) * C + c0 + tx];
  __syncthreads();
#pragma unroll
  for (int i = 0; i < 32; i += 8)
    dst[(size_t)(c0 + ty + i) * R + r0 + tx] = f2bf(tile[tx][ty + i]);
}

// ---------- f32 -> bf16 elementwise (4/thread) ----------
__global__ __launch_bounds__(256) void k_cvt(const float* __restrict__ src,
                                             unsigned short* __restrict__ dst, int n4) {
  int i = blockIdx.x * 256 + threadIdx.x;
  if (i < n4) {
    f32x4 v = *(const f32x4*)&src[(size_t)i * 4];
    u16x4 o;
#pragma unroll
    for (int j = 0; j < 4; ++j) o[j] = f2bf(v[j]);
    *(u16x4*)&dst[(size_t)i * 4] = o;
  }
}

// ---------- 256x256 tile bf16 GEMM, 2-dbuf stage-ahead counted-vmcnt pipeline ----------
__global__ __launch_bounds__(512, 2) void k_gemm(const unsigned short* __restrict__ A,
                                                 const unsigned short* __restrict__ Bw,
                                                 float* __restrict__ Cc,
                                                 int Nc, int Kd, int nxl) {
  __shared__ unsigned short shA[2][256 * 64];
  __shared__ unsigned short shB[2][256 * 64];
  const int tid = threadIdx.x, w = tid >> 6, l = tid & 63;
  const int xcd = blockIdx.x & 7, loc = blockIdx.x >> 3;
  const int m0 = ((xcd >> 1) * 4 + loc / nxl) * 256;
  const int n0 = ((xcd & 1) * nxl + loc % nxl) * 256;

  const int srow = l >> 3;                      // 0..7
  const int sw_colb = (((l & 7) ^ srow) << 4);  // inverse-swizzled source col (bytes)
  const int wrow = w * 8;
  const int NT = Kd >> 6;

#define GSTAGE(buf, t)                                                                      \
  {                                                                                         \
    const size_t kt = (size_t)(t) << 6;                                                     \
    _Pragma("unroll") for (int r = 0; r < 4; ++r) {                                         \
      const char* src = (const char*)A + ((size_t)(m0 + r * 64 + wrow + srow) * Kd + kt) * 2 + sw_colb; \
      __builtin_amdgcn_global_load_lds(                                                     \
          (__attribute__((address_space(1))) void*)src,                                     \
          (__attribute__((address_space(3))) void*)((char*)&shA[buf][0] + r * 8192 + w * 1024), \
          16, 0, 0);                                                                        \
    }                                                                                       \
    _Pragma("unroll") for (int r = 0; r < 4; ++r) {                                         \
      const char* src = (const char*)Bw + ((size_t)(n0 + r * 64 + wrow + srow) * Kd + kt) * 2 + sw_colb; \
      __builtin_amdgcn_global_load_lds(                                                     \
          (__attribute__((address_space(1))) void*)src,                                     \
          (__attribute__((address_space(3))) void*)((char*)&shB[buf][0] + r * 8192 + w * 1024), \
          16, 0, 0);                                                                        \
    }                                                                                       \
  }

  const int wm = w >> 2, wn = w & 3;  // 2M x 4N wave grid
  const int lr = l & 15, lg = l >> 4;
  f32x4 acc[8][4] = {};

  GSTAGE(0, 0);

  for (int t = 0; t < NT; ++t) {
    const int buf = t & 1;
    if (t + 1 < NT) {
      GSTAGE(buf ^ 1, t + 1);
      asm volatile("s_waitcnt vmcnt(8)" ::: "memory");  // tile t resident; t+1 in flight
    } else {
      asm volatile("s_waitcnt vmcnt(0)" ::: "memory");
    }
    __builtin_amdgcn_s_barrier();

    const char* sa = (const char*)&shA[buf][0];
    const char* sb = (const char*)&shB[buf][0];
#pragma unroll
    for (int kk = 0; kk < 2; ++kk) {
      const int cb = kk * 64 + lg * 16;
      const int cbx = cb ^ ((lr & 7) << 4);  // row&7 == lr&7 for all frag rows
      s16x8 af[8], bfr[4];
#pragma unroll
      for (int mi = 0; mi < 8; ++mi)
        af[mi] = *(const s16x8*)(sa + (wm * 128 + mi * 16 + lr) * 128 + cbx);
#pragma unroll
      for (int ni = 0; ni < 4; ++ni)
        bfr[ni] = *(const s16x8*)(sb + (wn * 64 + ni * 16 + lr) * 128 + cbx);
      __builtin_amdgcn_s_setprio(1);
#pragma unroll
      for (int mi = 0; mi < 8; ++mi)
#pragma unroll
        for (int ni = 0; ni < 4; ++ni)
          acc[mi][ni] = __builtin_amdgcn_mfma_f32_16x16x32_bf16(af[mi], bfr[ni], acc[mi][ni], 0, 0, 0);
      __builtin_amdgcn_s_setprio(0);
    }
    __builtin_amdgcn_s_barrier();  // protect dbuf reuse by next iter's stage
  }
#undef GSTAGE

#pragma unroll
  for (int mi = 0; mi < 8; ++mi)
#pragma unroll
    for (int ni = 0; ni < 4; ++ni) {
      size_t base = (size_t)(m0 + wm * 128 + mi * 16 + lg * 4) * Nc + (n0 + wn * 64 + ni * 16 + lr);
#pragma unroll
      for (int i = 0; i < 4; ++i)
        Cc[base + (size_t)i * Nc] = acc[mi][ni][i];
    }
}

// ---------- RMSNorm + RoPE for q/k channels of Y; writes bf16 Q[B][NQ][T][H], K[B][NKV][T][H] ----------
__global__ __launch_bounds__(256) void k_normrope(const float* __restrict__ Y,
                                                  const float* __restrict__ qsc,
                                                  const float* __restrict__ ksc,
                                                  const int* __restrict__ pos,
                                                  unsigned short* __restrict__ Q,
                                                  unsigned short* __restrict__ Kb) {
  __shared__ float s_sin[128], s_cos[128];
  const int bt = blockIdx.x;
  const int b = bt >> 11, t = bt & (TB - 1);
  const int tid = threadIdx.x;
  float p = (float)pos[bt];
  if (tid < 128) {
    float fr = (float)tid * (1.0f / 128.0f);
    float inv_ts = __expf(fr * -9.210340371976184f);  // 10000^-fr
    float ang = p * inv_ts;
    float sv, cv;
    sincosf(ang, &sv, &cv);
    s_sin[tid] = sv;
    s_cos[tid] = cv;
  }
  __syncthreads();
  const int w = tid >> 6, l = tid & 63;
  const int jj0 = (l & 31) * 4;
  for (int sidx = w; sidx < 12; sidx += 4) {  // 0..7 q heads, 8..11 k heads
    const float* src = Y + (size_t)bt * 4096 + sidx * 256;
    f32x4 v = *(const f32x4*)&src[l * 4];
    float ss = v[0] * v[0] + v[1] * v[1] + v[2] * v[2] + v[3] * v[3];
#pragma unroll
    for (int d = 1; d < 64; d <<= 1) ss += __shfl_xor(ss, d);
    float rs = rsqrtf(ss * (1.0f / 256.0f) + 1e-6f);
    const float* scp = (sidx < 8) ? qsc : ksc;
    float nv[4], res[4];
#pragma unroll
    for (int j = 0; j < 4; ++j) nv[j] = v[j] * rs * (1.0f + scp[l * 4 + j]);
#pragma unroll
    for (int j = 0; j < 4; ++j) {
      float o = __shfl_xor(nv[j], 32);
      float sn = s_sin[jj0 + j], cs = s_cos[jj0 + j];
      res[j] = (l < 32) ? (nv[j] * cs - o * sn) : (nv[j] * cs + o * sn);
    }
    float qs = (sidx < 8) ? 0.0625f : 1.0f;  // H^-0.5 = 1/16 folded into q
    u16x4 ob;
#pragma unroll
    for (int j = 0; j < 4; ++j) ob[j] = f2bf(res[j] * qs);
    if (sidx < 8) {
      size_t di = ((size_t)(b * NQ + sidx) * TB + t) * HDIM + l * 4;
      *(u16x4*)&Q[di] = ob;
    } else {
      size_t di = ((size_t)(b * NKV + (sidx - 8)) * TB + t) * HDIM + l * 4;
      *(u16x4*)&Kb[di] = ob;
    }
  }
}

// ---------- transpose v channels of Y -> VT[B][NKV][H][T] bf16 ----------
__global__ __launch_bounds__(256) void k_vtrans(const float* __restrict__ Y,
                                                unsigned short* __restrict__ VT) {
  __shared__ float tile[64][65];
  const int t0 = blockIdx.x * 64, h0 = blockIdx.y * 64;
  const int z = blockIdx.z;  // b*4+kh
  const int bq = z >> 2, kh = z & 3;
  const int tid = threadIdx.x;
#pragma unroll
  for (int rep = 0; rep < 16; ++rep) {
    int idx = rep * 256 + tid;
    int tr = idx >> 6, hc = idx & 63;
    tile[tr][hc] = Y[(size_t)(bq * TB + t0 + tr) * 4096 + 3072 + kh * 256 + h0 + hc];
  }
  __syncthreads();
#pragma unroll
  for (int rep = 0; rep < 16; ++rep) {
    int idx = rep * 256 + tid;
    int hr = idx >> 6, tc = idx & 63;
    VT[((size_t)z * 256 + h0 + hr) * TB + t0 + tc] = f2bf(tile[tc][hr]);
  }
}

// ---------- flash attention: counted-vmcnt pipeline, per-lane lsum, defer-rescale ----------
__global__ __launch_bounds__(256, 2) void k_attn(const unsigned short* __restrict__ Q,
                                                 const unsigned short* __restrict__ Kb,
                                                 const unsigned short* __restrict__ VT,
                                                 unsigned short* __restrict__ ENC) {
  __shared__ unsigned short shK[2][32 * 256];  // [s-row][h], 512B rows, XOR-swizzled
  __shared__ unsigned short shV[2][256 * 32];  // [h-row][s], 64B rows
  __shared__ unsigned short Pb[4][16 * 40];    // 80B rows
  const int tid = threadIdx.x, w = tid >> 6, l = tid & 63;
  const int bn = blockIdx.y;
  const int b = bn >> 3, n = bn & 7, kh = n >> 1;
  const int t0b = blockIdx.x * 64;
  const int t0 = t0b + w * 16;
  const int lr = l & 15, lg = l >> 4;
  const unsigned short* qp = Q + ((size_t)bn * TB + t0) * HDIM;
  const char* kbase = (const char*)(Kb + ((size_t)(b * NKV + kh) * TB) * HDIM);
  const char* vbase = (const char*)(VT + ((size_t)(b * NKV + kh) * HDIM) * TB);

  s16x8 aq[8];
#pragma unroll
  for (int kk = 0; kk < 8; ++kk)
    aq[kk] = *(const s16x8*)&qp[lr * HDIM + kk * 32 + lg * 8];

  f32x4 o[16] = {};
  float mrow[4], lsum[4];  // lsum is PER-LANE partial; reduced across 16 lanes at epilogue
#pragma unroll
  for (int i = 0; i < 4; ++i) { mrow[i] = -__builtin_inff(); lsum[i] = 0.f; }

  int lo = t0b - (WIN - 1);
  if (lo < 0) lo = 0;
  lo &= ~31;
  const int nsteps = (t0b + 32 - lo) / 32 + 1;

  const int k_row = (w << 1) + (l >> 5);
  const int k_colb = (l & 31) * 16;
  const int v_row = (w << 4) + (l >> 2);
  const int v_colb = (l & 3) * 16;
#define STAGE(buf, s0)                                                                       \
  {                                                                                          \
    _Pragma("unroll") for (int r = 0; r < 4; ++r) {                                          \
      int row = r * 8 + k_row;                                                               \
      int scol = k_colb ^ ((row & 7) << 4);                                                  \
      const char* src = kbase + (size_t)((s0) + row) * 512 + scol;                           \
      __builtin_amdgcn_global_load_lds(                                                      \
          (__attribute__((address_space(1))) void*)src,                                      \
          (__attribute__((address_space(3))) void*)((char*)&shK[buf][0] + r * 4096 + w * 1024), \
          16, 0, 0);                                                                         \
    }                                                                                        \
    _Pragma("unroll") for (int r = 0; r < 4; ++r) {                                          \
      int row = r * 64 + v_row;                                                              \
      const char* src = vbase + (size_t)row * (TB * 2) + (size_t)(s0) * 2 + v_colb;          \
      __builtin_amdgcn_global_load_lds(                                                      \
          (__attribute__((address_space(1))) void*)src,                                      \
          (__attribute__((address_space(3))) void*)((char*)&shV[buf][0] + r * 4096 + w * 1024), \
          16, 0, 0);                                                                         \
    }                                                                                        \
  }

  STAGE(0, lo);

  for (int step = 0; step < nsteps; ++step) {
    const int s0 = lo + step * 32;
    const int buf = step & 1;
    // issue next-tile loads FIRST, then counted wait: tile `step` confirmed resident,
    // tile step+1's 8 loads stay in flight across both barriers (T3/T4).
    if (step + 1 < nsteps) {
      STAGE(buf ^ 1, s0 + 32);
      asm volatile("s_waitcnt vmcnt(8)" ::: "memory");
    } else {
      asm volatile("s_waitcnt vmcnt(0)" ::: "memory");
    }
    __builtin_amdgcn_s_barrier();

    const bool active = (s0 <= t0 + 15) && (s0 + 31 >= t0 - (WIN - 1));
    if (active) {
      // QK^T from LDS (swizzled read)
      f32x4 sacc[2] = {};
      const char* kt = (const char*)&shK[buf][0];
      const int swz = (lr & 7) << 4;
#pragma unroll
      for (int cb = 0; cb < 2; ++cb) {
        const int rb = (cb * 16 + lr) * 512;
        s16x8 bk[8];
#pragma unroll
        for (int kk = 0; kk < 8; ++kk)
          bk[kk] = *(const s16x8*)(kt + rb + ((kk * 64 + lg * 16) ^ swz));
        __builtin_amdgcn_s_setprio(1);
#pragma unroll
        for (int kk = 0; kk < 8; ++kk)
          sacc[cb] = __builtin_amdgcn_mfma_f32_16x16x32_bf16(aq[kk], bk[kk], sacc[cb], 0, 0, 0);
        __builtin_amdgcn_s_setprio(0);
      }
      // mask (skipped for interior steps: wave-uniform branch)
      float svA_[4], svB_[4];
      const bool nomask = (s0 + 31 <= t0) && (s0 >= t0 - (WIN - 16));
      if (nomask) {
#pragma unroll
        for (int i = 0; i < 4; ++i) { svA_[i] = sacc[0][i]; svB_[i] = sacc[1][i]; }
      } else {
#pragma unroll
        for (int i = 0; i < 4; ++i) {
          int trow = t0 + lg * 4 + i;
          int sA = s0 + lr, sB = s0 + 16 + lr;
          svA_[i] = ((sA <= trow) && (trow - sA < WIN)) ? sacc[0][i] : KMASK;
          svB_[i] = ((sB <= trow) && (trow - sB < WIN)) ? sacc[1][i] : KMASK;
        }
      }
      // reduce-free threshold check (T13): only reduce+rescale when some score
      // exceeds its row's running max + 8
      bool ok = true;
#pragma unroll
      for (int i = 0; i < 4; ++i)
        ok = ok && (svA_[i] <= mrow[i] + 8.f) && (svB_[i] <= mrow[i] + 8.f);
      if (!__all(ok)) {
        float r_[4];
#pragma unroll
        for (int i = 0; i < 4; ++i) {
          float mx = fmaxf(svA_[i], svB_[i]);
#pragma unroll
          for (int d = 1; d < 16; d <<= 1) mx = fmaxf(mx, __shfl_xor(mx, d));
          float mnew = fmaxf(mrow[i], mx);
          r_[i] = __expf(mrow[i] - mnew);
          lsum[i] *= r_[i];
          mrow[i] = mnew;
        }
#pragma unroll
        for (int hb = 0; hb < 16; ++hb)
#pragma unroll
          for (int i = 0; i < 4; ++i) o[hb][i] *= r_[i];
      }
      // P = exp(S - m); per-lane lsum accumulation (no per-step reduce)
#pragma unroll
      for (int i = 0; i < 4; ++i) {
        float pa = __expf(svA_[i] - mrow[i]);
        float pb = __expf(svB_[i] - mrow[i]);
        lsum[i] += pa + pb;
        int row = lg * 4 + i;
        Pb[w][row * 40 + lr] = f2bf(pa);
        Pb[w][row * 40 + 16 + lr] = f2bf(pb);
      }
      asm volatile("s_waitcnt lgkmcnt(0)" ::: "memory");
      s16x8 pfrag = *(const s16x8*)&Pb[w][lr * 40 + lg * 8];
      // PV from LDS V-tile
      const char* vt = (const char*)&shV[buf][0];
      s16x8 vb[16];
#pragma unroll
      for (int hb = 0; hb < 16; ++hb)
        vb[hb] = *(const s16x8*)(vt + (hb * 16 + lr) * 64 + lg * 16);
      __builtin_amdgcn_s_setprio(1);
#pragma unroll
      for (int hb = 0; hb < 16; ++hb)
        o[hb] = __builtin_amdgcn_mfma_f32_16x16x32_bf16(pfrag, vb[hb], o[hb], 0, 0, 0);
      __builtin_amdgcn_s_setprio(0);
    }
    __builtin_amdgcn_s_barrier();  // protect dbuf overwrite by next step's STAGE
  }
#undef STAGE

  // epilogue: reduce per-lane lsum across the row's 16 lanes
#pragma unroll
  for (int i = 0; i < 4; ++i) {
    float s = lsum[i];
#pragma unroll
    for (int d = 1; d < 16; d <<= 1) s += __shfl_xor(s, d);
    lsum[i] = s;
  }
#pragma unroll
  for (int i = 0; i < 4; ++i) {
    int trow = t0 + lg * 4 + i;
    float inv = 1.0f / lsum[i];
    size_t rb = (size_t)(b * TB + trow) * 2048 + n * HDIM;
#pragma unroll
    for (int hb = 0; hb < 16; ++hb)
      ENC[rb + hb * 16 + lr] = f2bf(o[hb][i] * inv);
  }
}

extern "C" void kernel_launch(void* const* d_in, const int* in_sizes, int n_in,
                              void* d_out, int out_size, void* d_ws, size_t ws_size,
                              hipStream_t stream) {
  (void)in_sizes; (void)n_in; (void)out_size; (void)ws_size;
  const float* x = (const float*)d_in[0];
  const float* q_w = (const float*)d_in[1];
  const float* kv_w = (const float*)d_in[2];
  const float* qsc = (const float*)d_in[3];
  const float* ksc = (const float*)d_in[4];
  const float* out_w = (const float*)d_in[5];
  const int* pos = (const int*)d_in[6];
  float* out = (float*)d_out;

  char* ws = (char*)d_ws;
  unsigned short* W1 = (unsigned short*)(ws);              // 4096x2560 bf16 (20.97 MB)
  unsigned short* W3 = (unsigned short*)(ws + 20971520);   // 2560x2048 bf16 (10.49 MB)
  unsigned short* XB = (unsigned short*)(ws + 31457280);   // 4096x2560 bf16 (20.97 MB)
  float* Y = (float*)(ws + 52428800);                      // 4096x4096 f32  (67.1 MB)
  unsigned short* KB = (unsigned short*)(ws + 119537664);  // 2x4x2048x256 bf16 (8.39 MB)
  unsigned short* VT = (unsigned short*)(ws + 127926272);  // 2x4x256x2048 bf16 (8.39 MB)
  unsigned short* Qb = XB;                                 // reuse XB after GEMM1
  unsigned short* ENC = (unsigned short*)(ws + 52428800);  // reuse Y after norm/vtrans

  k_packw1<<<dim3(8, 80, 16), 256, 0, stream>>>(q_w, kv_w, W1);
  k_tconv<<<dim3(80, 64), 256, 0, stream>>>(out_w, W3, 2048, DIM);
  k_cvt<<<dim3(10240), 256, 0, stream>>>(x, XB, 2621440);
  // GEMM1: M=4096 (16 m-tiles), N=4096 (16 n-tiles) -> 256 blocks, XCD region 4m x 8n
  k_gemm<<<dim3(256), 512, 0, stream>>>(XB, W1, Y, 4096, DIM, 8);
  k_normrope<<<dim3(4096), 256, 0, stream>>>(Y, qsc, ksc, pos, Qb, KB);
  k_vtrans<<<dim3(32, 4, 8), 256, 0, stream>>>(Y, VT);
  k_attn<<<dim3(32, 16), 256, 0, stream>>>(Qb, KB, VT, ENC);
  // GEMM3: M=4096 (16 m-tiles), N=2560 (10 n-tiles) -> 160 blocks, XCD region 4m x 5n
  k_gemm<<<dim3(160), 512, 0, stream>>>(ENC, W3, out, DIM, 2048, 5);
}